// Round 1
// baseline (65762.708 us; speedup 1.0000x reference)
//
#include <hip/hip_runtime.h>
#include <math.h>

#define SCOPE __HIP_MEMORY_SCOPE_AGENT

constexpr int Bn = 64, Ln = 512, En = 128, Hn = 256, Tn = 512;
constexpr int NBLK = 256, NTHR = 512;

// ---- LDS layout (floats) ----
constexpr int OFF_CTX  = 0;                 // [128][256] ctx_proj slice
constexpr int OFF_SCR  = 32768;             // 4160 scratch union (s_part / att_part / u_s / staging)
constexpr int OFF_S    = OFF_SCR + 4160;    // scores [128]
constexpr int OFF_E    = OFF_S + 128;       // e      [128]
constexpr int OFF_MASK = OFF_E + 128;       // mask   [128]
constexpr int OFF_INPS = OFF_MASK + 128;    // inp    [256]
constexpr int OFF_VS   = OFF_INPS + 256;    // V      [256]
constexpr int OFF_GT   = OFF_VS + 256;      // gates  [4][64]
constexpr int OFF_GT2  = OFF_GT + 256;      // gate partials [256]
constexpr int OFF_WRED = OFF_GT2 + 256;     // small reduce [32]
constexpr int SMEM_FL  = OFF_WRED + 32;     // 38368 floats = 153472 B

// ---- output layout ----
constexpr size_t PTR_OFF = (size_t)Bn * Ln * Ln;        // alphas [b][t][l] first
constexpr size_t HF_OFF  = PTR_OFF + (size_t)Bn * Ln;
constexpr size_t CF_OFF  = HF_OFF + (size_t)Bn * Hn;

// ---- ws layout: 4KB barrier region, then floats ----
constexpr int WS_HT  = 0;                   // h_t (cell out) [64][256]
constexpr int WS_HID = WS_HT + Bn * Hn;     // hidden carry   [64][256]
constexpr int WS_INP = WS_HID + Bn * Hn;    // attn input     [64][256]
constexpr int WS_C   = WS_INP + Bn * Hn;    // cell state     [64][256]
constexpr int WS_MEX = WS_C + Bn * Hn;      // per-slice max  [64][4]
constexpr int WS_SEX = WS_MEX + 256;        // per-slice sum  [64][4]
constexpr int WS_CV  = WS_SEX + 256;        // cand val       [64][4]
constexpr int WS_CI  = WS_CV + 256;         // cand idx (int) [64][4]
constexpr int WS_IDX = WS_CI + 256;         // winner idx (int) [64]
constexpr int WS_ATT = WS_IDX + 64;         // att partials [64][4][256]
constexpr int WS_FLOATS = WS_ATT + Bn * 4 * Hn;   // 132160 floats

__device__ __forceinline__ float fast_tanh(float x) {
  const float e = __expf(2.0f * x);                 // 1 - 2/(1+e^{2x}); abs err ~1e-7
  return 1.0f - __fdividef(2.0f, 1.0f + e);
}
__device__ __forceinline__ float sigmoidf_(float x) {
  return 1.0f / (1.0f + expf(-x));
}
__device__ __forceinline__ float dot4(const float* __restrict__ w,
                                      const float* __restrict__ a,
                                      int n, float acc) {
  for (int k = 0; k < n; k += 4) {
    float4 wv = *(const float4*)&w[k];
    float4 av = *(const float4*)&a[k];
    acc = fmaf(wv.x, av.x, acc);
    acc = fmaf(wv.y, av.y, acc);
    acc = fmaf(wv.z, av.z, acc);
    acc = fmaf(wv.w, av.w, acc);
  }
  return acc;
}

// monotonic 2-level grid barrier: 8 leaf counters (32 blocks each) -> root -> gen
__device__ __forceinline__ void grid_barrier(unsigned* bar, int bid) {
  __syncthreads();
  if (threadIdx.x == 0) {
    unsigned* gen = bar + 512;
    unsigned g0 = __hip_atomic_load(gen, __ATOMIC_RELAXED, SCOPE);
    unsigned a = __hip_atomic_fetch_add(&bar[(bid & 7) * 32], 1u, __ATOMIC_ACQ_REL, SCOPE);
    if ((a & 31u) == 31u) {
      unsigned r = __hip_atomic_fetch_add(&bar[256], 1u, __ATOMIC_ACQ_REL, SCOPE);
      if ((r & 7u) == 7u)
        __hip_atomic_fetch_add(gen, 1u, __ATOMIC_RELEASE, SCOPE);
    }
    long spins = 0;
    while ((int)(__hip_atomic_load(gen, __ATOMIC_ACQUIRE, SCOPE) - g0) < 1) {
      __builtin_amdgcn_s_sleep(2);
      if (++spins > 30000000L) __builtin_trap();   // deadlock tripwire (~seconds)
    }
  }
  __syncthreads();
}

__global__ void __launch_bounds__(NTHR, 1)
decoder_main(const float* __restrict__ emb, const float* __restrict__ dec0,
             const float* __restrict__ h0,  const float* __restrict__ c0,
             const float* __restrict__ ctxg,const float* __restrict__ Wi,
             const float* __restrict__ bi,  const float* __restrict__ Wh,
             const float* __restrict__ bh,  const float* __restrict__ Wo,
             const float* __restrict__ bo,  const float* __restrict__ Wain,
             const float* __restrict__ bain,const float* __restrict__ Wactx,
             const float* __restrict__ bactx,const float* __restrict__ Vv,
             float* __restrict__ out, unsigned* __restrict__ bar,
             float* __restrict__ ws)
{
  extern __shared__ float sm[];
  float* ctx   = sm + OFF_CTX;
  float* scr   = sm + OFF_SCR;
  float* s_s   = sm + OFF_S;
  float* e_s   = sm + OFF_E;
  float* mask  = sm + OFF_MASK;
  float* inp_s = sm + OFF_INPS;
  float* V_s   = sm + OFF_VS;
  float* gt    = sm + OFF_GT;
  float* gt2   = sm + OFF_GT2;
  float* wred  = sm + OFF_WRED;

  const int bid = blockIdx.x, tid = threadIdx.x;
  // ctx-slice role
  const int cb = bid >> 2, ck = bid & 3;
  const int l0 = ck * 128;
  // P1 role: 4 h-rows (x4 gates) x 16 b
  const int p1_ht = bid >> 2, p1_bt = bid & 3;
  // P2/P5 GEMM role: 8 b x 8 rows
  const int g_bt = bid & 7, g_rt = bid >> 3;

  float* h_t_buf = ws + WS_HT;
  float* hid_buf = ws + WS_HID;
  float* inp_buf = ws + WS_INP;
  float* c_buf   = ws + WS_C;
  float* m_ex    = ws + WS_MEX;
  float* S_ex    = ws + WS_SEX;
  float* candv   = ws + WS_CV;
  int*   candi   = (int*)(ws + WS_CI);
  int*   idx_buf = (int*)(ws + WS_IDX);
  float* att_ex  = ws + WS_ATT;

  for (int i = tid; i < 128; i += NTHR) mask[i] = 1.0f;
  for (int i = tid; i < 256; i += NTHR) V_s[i] = Vv[i];

  // ---- one-time: ctx_proj slice into LDS:  ctx[l][g] = sum_k context[cb][l0+l][k]*Wactx[g][k] + bactx[g]
  {
    const int gc = tid & 31;   // g = gc*8..+8
    const int lg = tid >> 5;   // l = lg*8..+8
    float acc[8][8];
    #pragma unroll
    for (int a2 = 0; a2 < 8; ++a2)
      #pragma unroll
      for (int b2 = 0; b2 < 8; ++b2) acc[a2][b2] = 0.0f;
    float* stg_c = scr;          // [8][128] (k-major)
    float* stg_w = scr + 1024;   // [8][256] (k-major)
    for (int kc = 0; kc < 32; ++kc) {
      __syncthreads();
      for (int i = tid; i < 1024; i += NTHR) {
        int k = i & 7, l = i >> 3;
        stg_c[k * 128 + l] = ctxg[((size_t)(cb * Ln + l0 + l)) * Hn + kc * 8 + k];
      }
      for (int i = tid; i < 2048; i += NTHR) {
        int k = i & 7, g = i >> 3;
        stg_w[k * 256 + g] = Wactx[(size_t)g * Hn + kc * 8 + k];
      }
      __syncthreads();
      #pragma unroll
      for (int kk = 0; kk < 8; ++kk) {
        float cl[8], wg[8];
        #pragma unroll
        for (int j = 0; j < 8; ++j) cl[j] = stg_c[kk * 128 + lg * 8 + j];
        #pragma unroll
        for (int j = 0; j < 8; ++j) wg[j] = stg_w[kk * 256 + gc * 8 + j];
        #pragma unroll
        for (int li = 0; li < 8; ++li)
          #pragma unroll
          for (int gi = 0; gi < 8; ++gi)
            acc[li][gi] = fmaf(cl[li], wg[gi], acc[li][gi]);
      }
    }
    __syncthreads();
    #pragma unroll
    for (int li = 0; li < 8; ++li)
      #pragma unroll
      for (int gi = 0; gi < 8; ++gi)
        ctx[(lg * 8 + li) * Hn + gc * 8 + gi] = acc[li][gi] + bactx[gc * 8 + gi];
    __syncthreads();
  }

  for (int t = 0; t < Tn; ++t) {
    // ================= P1: gates + cell update =================
    {
      const int d = tid & 255, piece = tid >> 8;
      const int b_l = d & 15, h_l = (d >> 4) & 3, g = d >> 6;
      const int b = p1_bt * 16 + b_l;
      const int habs = p1_ht * 4 + h_l;
      const int r = g * 256 + habs;
      const float* hp = (t == 0) ? (h0 + (size_t)b * Hn) : (hid_buf + (size_t)b * Hn);
      const float* dp = (t == 0) ? (dec0 + (size_t)b * En)
                                 : (emb + ((size_t)b * Ln + idx_buf[b]) * En);
      float acc = 0.0f;
      const float* wh = Wh + (size_t)r * Hn;
      if (piece == 0) {
        acc = dot4(Wi + (size_t)r * En, dp, 128, acc);
        acc = dot4(wh, hp, 64, acc);
      } else {
        acc = dot4(wh + 64, hp + 64, 192, acc);
      }
      if (piece == 1) gt2[d] = acc;
      __syncthreads();
      if (piece == 0)
        gt[g * 64 + h_l * 16 + b_l] = acc + gt2[d] + bi[r] + bh[r];
      __syncthreads();
      if (tid < 64) {
        const int bl2 = tid & 15, hl2 = tid >> 4;
        const int b2 = p1_bt * 16 + bl2;
        const int h2 = p1_ht * 4 + hl2;
        const float gi_ = gt[0 * 64 + hl2 * 16 + bl2];
        const float gf_ = gt[1 * 64 + hl2 * 16 + bl2];
        const float gg_ = gt[2 * 64 + hl2 * 16 + bl2];
        const float go_ = gt[3 * 64 + hl2 * 16 + bl2];
        const float cold = (t == 0) ? c0[b2 * Hn + h2] : c_buf[b2 * Hn + h2];
        const float is = sigmoidf_(gi_);
        const float fs = sigmoidf_(gf_);
        const float gv = tanhf(gg_);
        const float os = sigmoidf_(go_);
        const float cnew = fs * cold + is * gv;
        const float htv = os * tanhf(cnew);
        c_buf[b2 * Hn + h2] = cnew;
        h_t_buf[b2 * Hn + h2] = htv;
        if (t == Tn - 1) out[CF_OFF + (size_t)b2 * Hn + h2] = cnew;
      }
    }
    grid_barrier(bar, bid);

    // ================= P2: inp = Wa_in @ h_t + ba_in =================
    {
      const int dotid = tid >> 3, piece = tid & 7;
      const int b = g_bt * 8 + (dotid >> 3);
      const int g = g_rt * 8 + (dotid & 7);
      float acc = dot4(Wain + (size_t)g * Hn + piece * 32,
                       h_t_buf + (size_t)b * Hn + piece * 32, 32, 0.0f);
      acc += __shfl_xor(acc, 1, 64);
      acc += __shfl_xor(acc, 2, 64);
      acc += __shfl_xor(acc, 4, 64);
      if (piece == 0) inp_buf[b * Hn + g] = acc + bain[g];
    }
    grid_barrier(bar, bid);

    // ================= P3a: scores + per-slice max =================
    {
      for (int i = tid; i < Hn; i += NTHR) inp_s[i] = inp_buf[cb * Hn + i];
      __syncthreads();
      const int hcq = tid & 63;   // h = hcq*4..+4
      const int lgq = tid >> 6;   // l-group 0..7
      const float4 rin = *(const float4*)&inp_s[hcq * 4];
      const float4 rv  = *(const float4*)&V_s[hcq * 4];
      for (int half = 0; half < 2; ++half) {
        #pragma unroll
        for (int li = 0; li < 8; ++li) {
          const int l = half * 64 + lgq * 8 + li;
          const float4 c4 = *(const float4*)&ctx[l * Hn + hcq * 4];
          float p;
          p = rv.x * fast_tanh(rin.x + c4.x);
          p = fmaf(rv.y, fast_tanh(rin.y + c4.y), p);
          p = fmaf(rv.z, fast_tanh(rin.z + c4.z), p);
          p = fmaf(rv.w, fast_tanh(rin.w + c4.w), p);
          scr[(lgq * 8 + li) * 65 + hcq] = p;
        }
        __syncthreads();
        if (tid < 64) {
          float s = 0.0f;
          for (int j = 0; j < 64; ++j) s += scr[tid * 65 + j];
          const int l = half * 64 + tid;
          s_s[l] = (mask[l] == 0.0f) ? -INFINITY : s;
        }
        __syncthreads();
      }
      if (tid < 128) {
        float v = s_s[tid];
        #pragma unroll
        for (int m = 1; m < 64; m <<= 1) v = fmaxf(v, __shfl_xor(v, m, 64));
        if ((tid & 63) == 0) wred[tid >> 6] = v;
      }
      __syncthreads();
      if (tid == 0) m_ex[cb * 4 + ck] = fmaxf(wred[0], wred[1]);
    }
    grid_barrier(bar, bid);

    // ================= P3b: e, S', candidate argmax, att partials =================
    {
      const float M = fmaxf(fmaxf(m_ex[cb * 4 + 0], m_ex[cb * 4 + 1]),
                            fmaxf(m_ex[cb * 4 + 2], m_ex[cb * 4 + 3]));
      if (tid < 128) {
        const float e = expf(s_s[tid] - M);
        e_s[tid] = e;
        float v = e;
        #pragma unroll
        for (int m = 1; m < 64; m <<= 1) v += __shfl_xor(v, m, 64);
        float cv = e; int ci = tid;
        #pragma unroll
        for (int m = 1; m < 64; m <<= 1) {
          const float ov = __shfl_xor(cv, m, 64);
          const int   oi = __shfl_xor(ci, m, 64);
          if (ov > cv || (ov == cv && oi < ci)) { cv = ov; ci = oi; }
        }
        if ((tid & 63) == 0) {
          wred[2 + (tid >> 6)] = v;
          wred[4 + (tid >> 6)] = cv;
          ((int*)wred)[6 + (tid >> 6)] = ci;
        }
      }
      __syncthreads();
      if (tid == 0) {
        S_ex[cb * 4 + ck] = wred[2] + wred[3];
        float bv = wred[4]; int bI = ((int*)wred)[6];
        const float v1 = wred[5]; const int i1 = ((int*)wred)[7];
        if (v1 > bv || (v1 == bv && i1 < bI)) { bv = v1; bI = i1; }
        candv[cb * 4 + ck] = bv;
        candi[cb * 4 + ck] = l0 + bI;
      }
      const int hcq = tid & 63, lgq = tid >> 6;
      float p0 = 0, p1 = 0, p2 = 0, p3 = 0;
      #pragma unroll
      for (int half = 0; half < 2; ++half)
        #pragma unroll
        for (int li = 0; li < 8; ++li) {
          const int l = half * 64 + lgq * 8 + li;
          const float ev = e_s[l];
          const float4 c4 = *(const float4*)&ctx[l * Hn + hcq * 4];
          p0 = fmaf(ev, c4.x, p0);
          p1 = fmaf(ev, c4.y, p1);
          p2 = fmaf(ev, c4.z, p2);
          p3 = fmaf(ev, c4.w, p3);
        }
      __syncthreads();
      *(float4*)&scr[lgq * 256 + hcq * 4] = make_float4(p0, p1, p2, p3);
      __syncthreads();
      if (tid < 256) {
        float a = 0.0f;
        #pragma unroll
        for (int r2 = 0; r2 < 8; ++r2) a += scr[r2 * 256 + tid];
        att_ex[(cb * 4 + ck) * 256 + tid] = a;
      }
    }
    grid_barrier(bar, bid);

    // ================= P5: alphas, pointer, mask, att combine, hidden GEMM =================
    {
      if (tid < 8) {
        const int b = g_bt * 8 + tid;
        wred[tid] = ((S_ex[b * 4 + 0] + S_ex[b * 4 + 1]) + S_ex[b * 4 + 2]) + S_ex[b * 4 + 3];
      }
      if (tid < 128) {
        const float Sb = ((S_ex[cb * 4 + 0] + S_ex[cb * 4 + 1]) + S_ex[cb * 4 + 2]) + S_ex[cb * 4 + 3];
        out[(size_t)cb * Ln * Ln + (size_t)t * Ln + l0 + tid] = e_s[tid] / Sb;
      }
      if (tid == 0) {
        float bv = candv[cb * 4 + 0]; int bI = candi[cb * 4 + 0];
        #pragma unroll
        for (int k2 = 1; k2 < 4; ++k2) {
          const float v2 = candv[cb * 4 + k2];
          const int i2 = candi[cb * 4 + k2];
          if (v2 > bv || (v2 == bv && i2 < bI)) { bv = v2; bI = i2; }
        }
        if ((bI >> 7) == ck) mask[bI & 127] = 0.0f;
        if (ck == 0) {
          idx_buf[cb] = bI;
          out[PTR_OFF + (size_t)cb * Ln + t] = (float)bI;
        }
      }
      __syncthreads();
      float* u_s = scr;   // [8][520]
      for (int i = tid; i < 8 * 512; i += NTHR) {
        const int b2 = i >> 9, k = i & 511;
        const int b = g_bt * 8 + b2;
        float v;
        if (k < 256) {
          const float s4 = ((att_ex[(b * 4 + 0) * 256 + k] + att_ex[(b * 4 + 1) * 256 + k])
                           + att_ex[(b * 4 + 2) * 256 + k]) + att_ex[(b * 4 + 3) * 256 + k];
          v = s4 / wred[b2];
        } else {
          v = h_t_buf[b * Hn + (k - 256)];
        }
        u_s[b2 * 520 + k] = v;
      }
      __syncthreads();
      {
        const int dotid = tid >> 3, piece = tid & 7;
        const int b2 = dotid >> 3, rr = dotid & 7;
        const int g = g_rt * 8 + rr;
        float acc = dot4(Wo + (size_t)g * 512 + piece * 64,
                         u_s + b2 * 520 + piece * 64, 64, 0.0f);
        acc += __shfl_xor(acc, 1, 64);
        acc += __shfl_xor(acc, 2, 64);
        acc += __shfl_xor(acc, 4, 64);
        if (piece == 0) {
          const int b = g_bt * 8 + b2;
          const float hv = tanhf(acc + bo[g]);
          hid_buf[b * Hn + g] = hv;
          if (t == Tn - 1) out[HF_OFF + (size_t)b * Hn + g] = hv;
        }
      }
    }
    grid_barrier(bar, bid);
  }
}

extern "C" void kernel_launch(void* const* d_in, const int* in_sizes, int n_in,
                              void* d_out, int out_size, void* d_ws, size_t ws_size,
                              hipStream_t stream) {
  (void)in_sizes; (void)n_in; (void)out_size; (void)ws_size;
  hipFuncSetAttribute(reinterpret_cast<const void*>(decoder_main),
                      hipFuncAttributeMaxDynamicSharedMemorySize, SMEM_FL * 4);
  // zero the barrier region (ws is poisoned 0xAA by the harness, and counters are monotonic per launch)
  hipMemsetAsync(d_ws, 0, 4096, stream);

  const float* emb   = (const float*)d_in[0];
  const float* dec0  = (const float*)d_in[1];
  const float* h0    = (const float*)d_in[2];
  const float* c0    = (const float*)d_in[3];
  const float* ctxg  = (const float*)d_in[4];
  const float* Wi    = (const float*)d_in[5];
  const float* bi    = (const float*)d_in[6];
  const float* Wh    = (const float*)d_in[7];
  const float* bh    = (const float*)d_in[8];
  const float* Wo    = (const float*)d_in[9];
  const float* bo    = (const float*)d_in[10];
  const float* Wain  = (const float*)d_in[11];
  const float* bain  = (const float*)d_in[12];
  const float* Wactx = (const float*)d_in[13];
  const float* bactx = (const float*)d_in[14];
  const float* V     = (const float*)d_in[15];

  unsigned* bar = (unsigned*)d_ws;
  float* wsf = (float*)((char*)d_ws + 4096);

  decoder_main<<<NBLK, NTHR, SMEM_FL * 4, stream>>>(
      emb, dec0, h0, c0, ctxg, Wi, bi, Wh, bh, Wo, bo, Wain, bain, Wactx, bactx, V,
      (float*)d_out, bar, wsf);
}

// Round 2
// 33202.750 us; speedup vs baseline: 1.9806x; 1.9806x over previous
//
#include <hip/hip_runtime.h>
#include <math.h>

#define SCOPE __HIP_MEMORY_SCOPE_AGENT

constexpr int Bn = 64, Ln = 512, En = 128, Hn = 256, Tn = 512;
constexpr int NBLK = 256, NTHR = 512;
constexpr int CTX_LD = 260;   // padded row stride (260%32=4 -> conflict-free column walks)

// ---- LDS layout (floats) ----
constexpr int OFF_CTX = 0;                   // [128][CTX_LD]
constexpr int OFF_SCR = 128 * CTX_LD;        // 3072 scratch (init staging / PV partials)
constexpr int OFF_US  = OFF_SCR + 2048;      // u vector [512] (aliases scr tail)
constexpr int OFF_X   = OFF_SCR + 3072;      // x = [dec(128); h(256)]
constexpr int OFF_HT  = OFF_X + 384;         // h_t full [256]
constexpr int OFF_INP = OFF_HT + 256;        // inp [256]
constexpr int OFF_SS  = OFF_INP + 256;       // scores slice [128]
constexpr int OFF_ES  = OFF_SS + 128;        // e slice [128]
constexpr int OFF_MK  = OFF_ES + 128;        // mask slice [128]
constexpr int OFF_CS  = OFF_MK + 128;        // c slice [64]
constexpr int OFF_VS  = OFF_CS + 64;         // V [256]
constexpr int OFF_BA  = OFF_VS + 256;        // bain [256]
constexpr int OFF_BS  = OFF_BA + 256;        // bi+bh for this block's rows [256]
constexpr int OFF_BO  = OFF_BS + 256;        // bo slice [64]
constexpr int OFF_GS  = OFF_BO + 64;         // gate dot results [256]
constexpr int OFF_WR  = OFF_GS + 256;        // small reduce scratch [64]
constexpr int SMEM_FL = OFF_WR + 64;         // 38848 floats = 155392 B

// ---- output layout ----
constexpr size_t PTR_OFF = (size_t)Bn * Ln * Ln;
constexpr size_t HF_OFF  = PTR_OFF + (size_t)Bn * Ln;
constexpr size_t CF_OFF  = HF_OFF + (size_t)Bn * Hn;

// ---- ws layout ----
// [0, 32KB): flags, 64 groups x 4 blocks x 32 uints (128B spacing)
// then per-group float region, stride 2048:
constexpr int WG_HT   = 0;      // h_t slices [256]
constexpr int WG_HID  = 256;    // hidden slices [256]
constexpr int WG_ATT  = 512;    // att partials [4][256]
constexpr int WG_M    = 1536;   // slice max [4]
constexpr int WG_S    = 1540;   // slice expsum [4]
constexpr int WG_CV   = 1544;   // cand score [4]
constexpr int WG_CI   = 1548;   // cand idx (int) [4]
constexpr int WG_STRIDE = 2048;

__device__ __forceinline__ float fast_tanh(float x) {
  const float e = __expf(2.0f * x);
  return 1.0f - __fdividef(2.0f, 1.0f + e);
}
__device__ __forceinline__ float sigmoidf_(float x) {
  return 1.0f / (1.0f + expf(-x));
}

// 4-block group barrier: flag-store + 4-reader poll (no RMW, no global storm)
__device__ __forceinline__ void group_barrier(unsigned* flags_g, int ck, unsigned tgt) {
  __syncthreads();
  if (threadIdx.x == 0)
    __hip_atomic_store(&flags_g[ck * 32], tgt, __ATOMIC_RELEASE, SCOPE);
  if (threadIdx.x < 4) {
    long spins = 0;
    while (__hip_atomic_load(&flags_g[threadIdx.x * 32], __ATOMIC_ACQUIRE, SCOPE) < tgt) {
      __builtin_amdgcn_s_sleep(1);
      if (++spins > 100000000L) __builtin_trap();   // deadlock tripwire
    }
  }
  __syncthreads();
}

__global__ void __launch_bounds__(NTHR)
decoder_main(const float* __restrict__ emb, const float* __restrict__ dec0,
             const float* __restrict__ h0,  const float* __restrict__ c0,
             const float* __restrict__ ctxg,const float* __restrict__ Wi,
             const float* __restrict__ bi,  const float* __restrict__ Wh,
             const float* __restrict__ bh,  const float* __restrict__ Wo,
             const float* __restrict__ bo,  const float* __restrict__ Wain,
             const float* __restrict__ bain,const float* __restrict__ Wactx,
             const float* __restrict__ bactx,const float* __restrict__ Vv,
             float* __restrict__ out, unsigned* __restrict__ flags,
             float* __restrict__ wsd)
{
  extern __shared__ float sm[];
  float* ctx   = sm + OFF_CTX;
  float* scr   = sm + OFF_SCR;
  float* u_s   = sm + OFF_US;
  float* x_s   = sm + OFF_X;
  float* ht_s  = sm + OFF_HT;
  float* inp_s = sm + OFF_INP;
  float* s_s   = sm + OFF_SS;
  float* e_s   = sm + OFF_ES;
  float* mask_s= sm + OFF_MK;
  float* c_s   = sm + OFF_CS;
  float* V_s   = sm + OFF_VS;
  float* bain_s= sm + OFF_BA;
  float* bsum_s= sm + OFF_BS;
  float* bo_s  = sm + OFF_BO;
  float* gsum  = sm + OFF_GS;
  float* wred  = sm + OFF_WR;
  int*   wredi = (int*)wred;

  const int tid = threadIdx.x, bid = blockIdx.x;
  const int g = bid & 63, ck = bid >> 6;     // group=batch b, ck=l-slice
  const int b = g;
  const int l0 = ck * 128;
  const int lane8 = tid & 7, rloc = tid >> 3;

  unsigned* flags_g = flags + (g * 4) * 32;
  float* wg = wsd + (size_t)g * WG_STRIDE;
  int* wg_ci = (int*)(wg + WG_CI);

  // ---- preloads ----
  if (tid < 128) mask_s[tid] = 1.0f;
  if (tid < 256) {
    V_s[tid] = Vv[tid];
    bain_s[tid] = bain[tid];
    const int gg = tid >> 6, hl = tid & 63;
    const int r = gg * 256 + ck * 64 + hl;
    bsum_s[tid] = bi[r] + bh[r];
  }
  if (tid < 64) {
    bo_s[tid] = bo[ck * 64 + tid];
    c_s[tid] = c0[(size_t)b * Hn + ck * 64 + tid];
  }

  // ---- one-time ctx_proj slice into LDS ----
  {
    const int gc = tid & 31;   // g-block of 8
    const int lg = tid >> 5;   // l-block of 8
    float acc[8][8];
    #pragma unroll
    for (int a2 = 0; a2 < 8; ++a2)
      #pragma unroll
      for (int b2 = 0; b2 < 8; ++b2) acc[a2][b2] = 0.0f;
    float* stg_c = scr;          // [8][128]
    float* stg_w = scr + 1024;   // [8][256]
    for (int kc = 0; kc < 32; ++kc) {
      __syncthreads();
      for (int i = tid; i < 1024; i += NTHR) {
        int k = i & 7, l = i >> 3;
        stg_c[k * 128 + l] = ctxg[((size_t)(b * Ln + l0 + l)) * Hn + kc * 8 + k];
      }
      for (int i = tid; i < 2048; i += NTHR) {
        int k = i & 7, gg = i >> 3;
        stg_w[k * 256 + gg] = Wactx[(size_t)gg * Hn + kc * 8 + k];
      }
      __syncthreads();
      #pragma unroll
      for (int kk = 0; kk < 8; ++kk) {
        float cl[8], wgt[8];
        #pragma unroll
        for (int j = 0; j < 8; ++j) cl[j] = stg_c[kk * 128 + lg * 8 + j];
        #pragma unroll
        for (int j = 0; j < 8; ++j) wgt[j] = stg_w[kk * 256 + gc * 8 + j];
        #pragma unroll
        for (int li = 0; li < 8; ++li)
          #pragma unroll
          for (int gi = 0; gi < 8; ++gi)
            acc[li][gi] = fmaf(cl[li], wgt[gi], acc[li][gi]);
      }
    }
    __syncthreads();
    #pragma unroll
    for (int li = 0; li < 8; ++li)
      #pragma unroll
      for (int gi = 0; gi < 8; ++gi)
        ctx[(lg * 8 + li) * CTX_LD + gc * 8 + gi] = acc[li][gi] + bactx[gc * 8 + gi];
  }
  __syncthreads();

  unsigned tgt = 1;
  int widx = 0;

  for (int t = 0; t < Tn; ++t) {
    // ============ Phase A: gates + cell (rows for h-slice [64ck,64ck+64), all 4 gates) ============
    {
      if (tid < 384) {
        float v;
        if (tid < 128) v = (t == 0) ? dec0[(size_t)b * En + tid]
                                    : emb[((size_t)b * Ln + widx) * En + tid];
        else           v = (t == 0) ? h0[(size_t)b * Hn + (tid - 128)]
                                    : wg[WG_HID + (tid - 128)];
        x_s[tid] = v;
      }
      __syncthreads();
      float gacc[4];
      #pragma unroll
      for (int m = 0; m < 4; ++m) {
        const int r = m * 256 + ck * 64 + rloc;       // gate m, h = ck*64+rloc
        const float* wi = Wi + (size_t)r * En;
        const float* wh = Wh + (size_t)r * Hn;
        float acc = 0.0f;
        #pragma unroll
        for (int i = 0; i < 4; ++i) {
          const int k = lane8 * 4 + i * 32;
          const float4 w4 = *(const float4*)&wi[k];
          const float4 x4 = *(const float4*)&x_s[k];
          acc = fmaf(w4.x, x4.x, fmaf(w4.y, x4.y, fmaf(w4.z, x4.z, fmaf(w4.w, x4.w, acc))));
        }
        #pragma unroll
        for (int i = 0; i < 8; ++i) {
          const int k = lane8 * 4 + i * 32;
          const float4 w4 = *(const float4*)&wh[k];
          const float4 x4 = *(const float4*)&x_s[128 + k];
          acc = fmaf(w4.x, x4.x, fmaf(w4.y, x4.y, fmaf(w4.z, x4.z, fmaf(w4.w, x4.w, acc))));
        }
        acc += __shfl_xor(acc, 1, 64);
        acc += __shfl_xor(acc, 2, 64);
        acc += __shfl_xor(acc, 4, 64);
        gacc[m] = acc;
      }
      if (lane8 == 0) {
        #pragma unroll
        for (int m = 0; m < 4; ++m) gsum[m * 64 + rloc] = gacc[m];
      }
      __syncthreads();
      if (tid < 64) {
        const float iv = gsum[tid]       + bsum_s[tid];
        const float fv = gsum[64 + tid]  + bsum_s[64 + tid];
        const float gv = gsum[128 + tid] + bsum_s[128 + tid];
        const float ov = gsum[192 + tid] + bsum_s[192 + tid];
        const float cold = c_s[tid];
        const float cn = sigmoidf_(fv) * cold + sigmoidf_(iv) * tanhf(gv);
        const float htv = sigmoidf_(ov) * tanhf(cn);
        c_s[tid] = cn;
        wg[WG_HT + ck * 64 + tid] = htv;
        if (t == Tn - 1) out[CF_OFF + (size_t)b * Hn + ck * 64 + tid] = cn;
      }
    }
    group_barrier(flags_g, ck, tgt++);

    // ============ Phase B: inp (redundant), scores slice, local softmax stats, PV partial ============
    {
      if (tid < 256) ht_s[tid] = wg[WG_HT + tid];
      __syncthreads();
      // inp = Wain @ h_t + bain  (full 256, redundant per block)
      float iacc[4];
      #pragma unroll
      for (int m = 0; m < 4; ++m) {
        const int row = m * 64 + rloc;
        const float* wa = Wain + (size_t)row * Hn;
        float acc = 0.0f;
        #pragma unroll
        for (int i = 0; i < 8; ++i) {
          const int k = lane8 * 4 + i * 32;
          const float4 w4 = *(const float4*)&wa[k];
          const float4 x4 = *(const float4*)&ht_s[k];
          acc = fmaf(w4.x, x4.x, fmaf(w4.y, x4.y, fmaf(w4.z, x4.z, fmaf(w4.w, x4.w, acc))));
        }
        acc += __shfl_xor(acc, 1, 64);
        acc += __shfl_xor(acc, 2, 64);
        acc += __shfl_xor(acc, 4, 64);
        iacc[m] = acc;
      }
      if (lane8 == 0) {
        #pragma unroll
        for (int m = 0; m < 4; ++m) inp_s[m * 64 + rloc] = iacc[m] + bain_s[m * 64 + rloc];
      }
      __syncthreads();
      // scores: l = tid>>2 (0..127), q = tid&3 covers h-quarter
      {
        const int l = tid >> 2, q = tid & 3;
        float p = 0.0f;
        #pragma unroll
        for (int i = 0; i < 16; ++i) {
          const int h4 = q * 64 + i * 4;
          const float4 c4 = *(const float4*)&ctx[l * CTX_LD + h4];
          const float4 in4 = *(const float4*)&inp_s[h4];
          const float4 v4 = *(const float4*)&V_s[h4];
          p = fmaf(v4.x, fast_tanh(in4.x + c4.x), p);
          p = fmaf(v4.y, fast_tanh(in4.y + c4.y), p);
          p = fmaf(v4.z, fast_tanh(in4.z + c4.z), p);
          p = fmaf(v4.w, fast_tanh(in4.w + c4.w), p);
        }
        p += __shfl_xor(p, 1, 64);
        p += __shfl_xor(p, 2, 64);
        if (q == 0) s_s[l] = (mask_s[l] == 0.0f) ? -INFINITY : p;
      }
      __syncthreads();
      if (tid < 128) {
        float v = s_s[tid];
        #pragma unroll
        for (int m = 1; m < 64; m <<= 1) v = fmaxf(v, __shfl_xor(v, m, 64));
        if ((tid & 63) == 0) wred[tid >> 6] = v;
      }
      __syncthreads();
      if (tid == 0) {
        const float mv = fmaxf(wred[0], wred[1]);
        wred[2] = mv;
        wg[WG_M + ck] = mv;
      }
      __syncthreads();
      if (tid < 128) {
        const float mv = wred[2];
        const float sv = s_s[tid];
        const float e = (mask_s[tid] == 0.0f) ? 0.0f : expf(sv - mv);
        e_s[tid] = e;
        float ssum = e;
        #pragma unroll
        for (int m = 1; m < 64; m <<= 1) ssum += __shfl_xor(ssum, m, 64);
        float cv = sv; int ci = tid;
        #pragma unroll
        for (int m = 1; m < 64; m <<= 1) {
          const float ov = __shfl_xor(cv, m, 64);
          const int   oi = __shfl_xor(ci, m, 64);
          if (ov > cv || (ov == cv && oi < ci)) { cv = ov; ci = oi; }
        }
        if ((tid & 63) == 0) {
          wred[4 + (tid >> 6)] = ssum;
          wred[8 + (tid >> 6)] = cv;
          wredi[12 + (tid >> 6)] = ci;
        }
      }
      __syncthreads();
      if (tid == 0) {
        wg[WG_S + ck] = wred[4] + wred[5];
        float bv = wred[8]; int bI = wredi[12];
        const float v1 = wred[9]; const int i1 = wredi[13];
        if (v1 > bv || (v1 == bv && i1 < bI)) { bv = v1; bI = i1; }
        wg[WG_CV + ck] = bv;
        wg_ci[ck] = l0 + bI;
      }
      // PV partial: att_k[h] = sum_l e_l * ctx[l][h]
      {
        const int h4g = tid & 63, lgq = tid >> 6;
        float p0 = 0, p1 = 0, p2 = 0, p3 = 0;
        #pragma unroll
        for (int li = 0; li < 16; ++li) {
          const int l = lgq * 16 + li;
          const float ev = e_s[l];
          const float4 c4 = *(const float4*)&ctx[l * CTX_LD + h4g * 4];
          p0 = fmaf(ev, c4.x, p0);
          p1 = fmaf(ev, c4.y, p1);
          p2 = fmaf(ev, c4.z, p2);
          p3 = fmaf(ev, c4.w, p3);
        }
        *(float4*)&scr[lgq * 256 + h4g * 4] = make_float4(p0, p1, p2, p3);
      }
      __syncthreads();
      if (tid < 256) {
        float a = 0.0f;
        #pragma unroll
        for (int r2 = 0; r2 < 8; ++r2) a += scr[r2 * 256 + tid];
        wg[WG_ATT + ck * 256 + tid] = a;
      }
    }
    group_barrier(flags_g, ck, tgt++);

    // ============ Phase C: merge softmax, alphas, pointer, mask, u, hidden slice ============
    {
      if (tid < 4) {
        wred[16 + tid] = wg[WG_M + tid];
        wred[20 + tid] = wg[WG_S + tid];
        wred[24 + tid] = wg[WG_CV + tid];
        wredi[28 + tid] = wg_ci[tid];
      }
      __syncthreads();
      const float M = fmaxf(fmaxf(wred[16], wred[17]), fmaxf(wred[18], wred[19]));
      const float sc0 = expf(wred[16] - M), sc1 = expf(wred[17] - M);
      const float sc2 = expf(wred[18] - M), sc3 = expf(wred[19] - M);
      const float S_tot = fmaf(sc0, wred[20], fmaf(sc1, wred[21], fmaf(sc2, wred[22], sc3 * wred[23])));
      const float sck = (ck == 0) ? sc0 : (ck == 1) ? sc1 : (ck == 2) ? sc2 : sc3;
      if (tid < 128)
        out[(size_t)b * Ln * Ln + (size_t)t * Ln + l0 + tid] = e_s[tid] * (sck / S_tot);
      // winner argmax (redundant on all threads; key = raw score, tie -> lower idx)
      {
        float bv = wred[24]; int bI = wredi[28];
        #pragma unroll
        for (int k2 = 1; k2 < 4; ++k2) {
          const float v2 = wred[24 + k2];
          const int i2 = wredi[28 + k2];
          if (v2 > bv || (v2 == bv && i2 < bI)) { bv = v2; bI = i2; }
        }
        widx = bI;
      }
      if (tid == 0) {
        if (widx >= l0 && widx < l0 + 128) mask_s[widx - l0] = 0.0f;
        if (ck == 0) out[PTR_OFF + (size_t)b * Ln + t] = (float)widx;
      }
      // u = [att_combined(256); h_t(256)]
      if (tid < 256) {
        const float a = fmaf(wg[WG_ATT + tid], sc0,
                        fmaf(wg[WG_ATT + 256 + tid], sc1,
                        fmaf(wg[WG_ATT + 512 + tid], sc2,
                             wg[WG_ATT + 768 + tid] * sc3)));
        u_s[tid] = a / S_tot;
      } else {
        u_s[tid] = ht_s[tid - 256];
      }
      __syncthreads();
      // hidden slice: rows [64ck, 64ck+64)
      {
        const int row = ck * 64 + rloc;
        const float* wo = Wo + (size_t)row * (2 * Hn);
        float acc = 0.0f;
        #pragma unroll
        for (int i = 0; i < 16; ++i) {
          const int k = lane8 * 4 + i * 32;
          const float4 w4 = *(const float4*)&wo[k];
          const float4 x4 = *(const float4*)&u_s[k];
          acc = fmaf(w4.x, x4.x, fmaf(w4.y, x4.y, fmaf(w4.z, x4.z, fmaf(w4.w, x4.w, acc))));
        }
        acc += __shfl_xor(acc, 1, 64);
        acc += __shfl_xor(acc, 2, 64);
        acc += __shfl_xor(acc, 4, 64);
        if (lane8 == 0) {
          const float hv = tanhf(acc + bo_s[rloc]);
          wg[WG_HID + row] = hv;
          if (t == Tn - 1) out[HF_OFF + (size_t)b * Hn + row] = hv;
        }
      }
    }
    group_barrier(flags_g, ck, tgt++);
  }
}

extern "C" void kernel_launch(void* const* d_in, const int* in_sizes, int n_in,
                              void* d_out, int out_size, void* d_ws, size_t ws_size,
                              hipStream_t stream) {
  (void)in_sizes; (void)n_in; (void)out_size; (void)ws_size;
  hipFuncSetAttribute(reinterpret_cast<const void*>(decoder_main),
                      hipFuncAttributeMaxDynamicSharedMemorySize, SMEM_FL * 4);
  hipMemsetAsync(d_ws, 0, 32768, stream);   // zero group flags each launch/replay

  const float* emb   = (const float*)d_in[0];
  const float* dec0  = (const float*)d_in[1];
  const float* h0    = (const float*)d_in[2];
  const float* c0    = (const float*)d_in[3];
  const float* ctxg  = (const float*)d_in[4];
  const float* Wi    = (const float*)d_in[5];
  const float* bi    = (const float*)d_in[6];
  const float* Wh    = (const float*)d_in[7];
  const float* bh    = (const float*)d_in[8];
  const float* Wo    = (const float*)d_in[9];
  const float* bo    = (const float*)d_in[10];
  const float* Wain  = (const float*)d_in[11];
  const float* bain  = (const float*)d_in[12];
  const float* Wactx = (const float*)d_in[13];
  const float* bactx = (const float*)d_in[14];
  const float* V     = (const float*)d_in[15];

  unsigned* flags = (unsigned*)d_ws;
  float* wsd = (float*)d_ws + 8192;

  decoder_main<<<NBLK, NTHR, SMEM_FL * 4, stream>>>(
      emb, dec0, h0, c0, ctxg, Wi, bi, Wh, bh, Wo, bo, Wain, bain, Wactx, bactx, V,
      (float*)d_out, flags, wsd);
}

// Round 3
// 18536.462 us; speedup vs baseline: 3.5477x; 1.7912x over previous
//
#include <hip/hip_runtime.h>
#include <math.h>

#define SCOPE __HIP_MEMORY_SCOPE_AGENT

constexpr int Bn = 64, Ln = 512, En = 128, Hn = 256, Tn = 512;
constexpr int NBLK = 256, NTHR = 512;
constexpr int CTX_LD = 260;   // padded row stride

// ---- LDS layout (floats) ----
constexpr int OFF_CTX = 0;                   // [128][CTX_LD]
constexpr int OFF_SCR = 128 * CTX_LD;        // 3072 scratch (init staging / PV partials / u)
constexpr int OFF_US  = OFF_SCR + 2048;      // u vector [512]
constexpr int OFF_X   = OFF_SCR + 3072;      // x = [dec(128); h(256)]
constexpr int OFF_HT  = OFF_X + 384;         // h_t full [256]
constexpr int OFF_INP = OFF_HT + 256;        // inp [256]
constexpr int OFF_SS  = OFF_INP + 256;       // scores slice [128]
constexpr int OFF_ES  = OFF_SS + 128;        // e slice [128]
constexpr int OFF_MK  = OFF_ES + 128;        // mask slice [128]
constexpr int OFF_CS  = OFF_MK + 128;        // c slice [64]
constexpr int OFF_VS  = OFF_CS + 64;         // V [256]
constexpr int OFF_BA  = OFF_VS + 256;        // bain [256]
constexpr int OFF_BS  = OFF_BA + 256;        // bi+bh rows [256]
constexpr int OFF_BO  = OFF_BS + 256;        // bo slice [64]
constexpr int OFF_GS  = OFF_BO + 64;         // gate dot results [256]
constexpr int OFF_WR  = OFF_GS + 256;        // small reduce scratch [64]
constexpr int OFF_HTL = OFF_WR + 64;         // local h_t slice [64]
constexpr int SMEM_FL = OFF_HTL + 64;        // 38912 floats = 155648 B

// ---- output layout ----
constexpr size_t PTR_OFF = (size_t)Bn * Ln * Ln;
constexpr size_t HF_OFF  = PTR_OFF + (size_t)Bn * Ln;
constexpr size_t CF_OFF  = HF_OFF + (size_t)Bn * Hn;

// ---- ws: [0,32KB) flags (64 groups x 4 x 32 uints); then per-group floats ----
constexpr int WG_HT   = 0;      // h_t slices [256]
constexpr int WG_HID  = 256;    // hidden slices [256]
constexpr int WG_ATT  = 512;    // att partials [4][256]
constexpr int WG_P    = 1536;   // inp partials [4][256]
constexpr int WG_M    = 2560;   // slice max [4]
constexpr int WG_S    = 2564;   // slice expsum [4]
constexpr int WG_CV   = 2568;   // cand score [4]
constexpr int WG_CI   = 2572;   // cand idx (int) [4]
constexpr int WG_STRIDE = 2624;

__device__ __forceinline__ float fast_tanh(float x) {
  const float e = __expf(2.0f * x);
  return 1.0f - __fdividef(2.0f, 1.0f + e);
}
__device__ __forceinline__ float sigmoidf_(float x) {
  return 1.0f / (1.0f + expf(-x));
}
// relaxed agent-scope (LLC) accessors: sc0|sc1, NO buffer_inv / cache nuking
__device__ __forceinline__ void llc_storef(float* p, float v) {
  __hip_atomic_store(p, v, __ATOMIC_RELAXED, SCOPE);
}
__device__ __forceinline__ float llc_loadf(const float* p) {
  return __hip_atomic_load(p, __ATOMIC_RELAXED, SCOPE);
}
__device__ __forceinline__ void llc_storei(int* p, int v) {
  __hip_atomic_store(p, v, __ATOMIC_RELAXED, SCOPE);
}
__device__ __forceinline__ int llc_loadi(const int* p) {
  return __hip_atomic_load(p, __ATOMIC_RELAXED, SCOPE);
}

// 4-block group barrier via relaxed LLC flags.
// Correctness: every wave drains vmcnt(0) before s_barrier (explicit asm +
// compiler-emitted drain), so all data stores (sc0|sc1 -> LLC) are acked at
// the coherence point before thread 0 publishes the flag.
__device__ __forceinline__ void group_barrier(unsigned* flags_g, int ck, unsigned tgt) {
  asm volatile("s_waitcnt vmcnt(0)" ::: "memory");
  __syncthreads();
  if (threadIdx.x == 0)
    __hip_atomic_store(&flags_g[ck * 32], tgt, __ATOMIC_RELAXED, SCOPE);
  if (threadIdx.x < 4) {
    long spins = 0;
    while (__hip_atomic_load(&flags_g[threadIdx.x * 32], __ATOMIC_RELAXED, SCOPE) < tgt) {
      __builtin_amdgcn_s_sleep(2);
      if (++spins > 50000000L) __builtin_trap();   // deadlock tripwire
    }
  }
  __syncthreads();
  asm volatile("" ::: "memory");
}

__global__ void __launch_bounds__(NTHR)
decoder_main(const float* __restrict__ emb, const float* __restrict__ dec0,
             const float* __restrict__ h0,  const float* __restrict__ c0,
             const float* __restrict__ ctxg,const float* __restrict__ Wi,
             const float* __restrict__ bi,  const float* __restrict__ Wh,
             const float* __restrict__ bh,  const float* __restrict__ Wo,
             const float* __restrict__ bo,  const float* __restrict__ Wain,
             const float* __restrict__ bain,const float* __restrict__ Wactx,
             const float* __restrict__ bactx,const float* __restrict__ Vv,
             float* __restrict__ out, unsigned* __restrict__ flags,
             float* __restrict__ wsd)
{
  extern __shared__ float sm[];
  float* ctx   = sm + OFF_CTX;
  float* scr   = sm + OFF_SCR;
  float* u_s   = sm + OFF_US;
  float* x_s   = sm + OFF_X;
  float* ht_s  = sm + OFF_HT;
  float* inp_s = sm + OFF_INP;
  float* s_s   = sm + OFF_SS;
  float* e_s   = sm + OFF_ES;
  float* mask_s= sm + OFF_MK;
  float* c_s   = sm + OFF_CS;
  float* V_s   = sm + OFF_VS;
  float* bain_s= sm + OFF_BA;
  float* bsum_s= sm + OFF_BS;
  float* bo_s  = sm + OFF_BO;
  float* gsum  = sm + OFF_GS;
  float* wred  = sm + OFF_WR;
  float* htl_s = sm + OFF_HTL;
  int*   wredi = (int*)wred;

  const int tid = threadIdx.x, bid = blockIdx.x;
  const int g = bid & 63, ck = bid >> 6;
  const int b = g;
  const int l0 = ck * 128;
  const int lane8 = tid & 7, rloc = tid >> 3;

  unsigned* flags_g = flags + (g * 4) * 32;
  float* wg = wsd + (size_t)g * WG_STRIDE;
  int* wg_ci = (int*)(wg + WG_CI);

  // ---- preloads ----
  if (tid < 128) mask_s[tid] = 1.0f;
  if (tid < 256) {
    V_s[tid] = Vv[tid];
    bain_s[tid] = bain[tid];
    const int gg = tid >> 6, hl = tid & 63;
    const int r = gg * 256 + ck * 64 + hl;
    bsum_s[tid] = bi[r] + bh[r];
  }
  if (tid < 64) {
    bo_s[tid] = bo[ck * 64 + tid];
    c_s[tid] = c0[(size_t)b * Hn + ck * 64 + tid];
  }

  // ---- one-time ctx_proj slice into LDS ----
  {
    const int gc = tid & 31;
    const int lg = tid >> 5;
    float acc[8][8];
    #pragma unroll
    for (int a2 = 0; a2 < 8; ++a2)
      #pragma unroll
      for (int b2 = 0; b2 < 8; ++b2) acc[a2][b2] = 0.0f;
    float* stg_c = scr;
    float* stg_w = scr + 1024;
    for (int kc = 0; kc < 32; ++kc) {
      __syncthreads();
      for (int i = tid; i < 1024; i += NTHR) {
        int k = i & 7, l = i >> 3;
        stg_c[k * 128 + l] = ctxg[((size_t)(b * Ln + l0 + l)) * Hn + kc * 8 + k];
      }
      for (int i = tid; i < 2048; i += NTHR) {
        int k = i & 7, gg = i >> 3;
        stg_w[k * 256 + gg] = Wactx[(size_t)gg * Hn + kc * 8 + k];
      }
      __syncthreads();
      #pragma unroll
      for (int kk = 0; kk < 8; ++kk) {
        float cl[8], wgt[8];
        #pragma unroll
        for (int j = 0; j < 8; ++j) cl[j] = stg_c[kk * 128 + lg * 8 + j];
        #pragma unroll
        for (int j = 0; j < 8; ++j) wgt[j] = stg_w[kk * 256 + gc * 8 + j];
        #pragma unroll
        for (int li = 0; li < 8; ++li)
          #pragma unroll
          for (int gi = 0; gi < 8; ++gi)
            acc[li][gi] = fmaf(cl[li], wgt[gi], acc[li][gi]);
      }
    }
    __syncthreads();
    #pragma unroll
    for (int li = 0; li < 8; ++li)
      #pragma unroll
      for (int gi = 0; gi < 8; ++gi)
        ctx[(lg * 8 + li) * CTX_LD + gc * 8 + gi] = acc[li][gi] + bactx[gc * 8 + gi];
  }
  __syncthreads();

  unsigned tgt = 1;
  int widx = 0;

  for (int t = 0; t < Tn; ++t) {
    // ============ Phase A: gates + cell + h_t slice + inp partial ============
    {
      if (tid < 384) {
        float v;
        if (tid < 128) v = (t == 0) ? dec0[(size_t)b * En + tid]
                                    : emb[((size_t)b * Ln + widx) * En + tid];
        else           v = (t == 0) ? h0[(size_t)b * Hn + (tid - 128)]
                                    : llc_loadf(wg + WG_HID + (tid - 128));
        x_s[tid] = v;
      }
      __syncthreads();
      float gacc[4];
      #pragma unroll
      for (int m = 0; m < 4; ++m) {
        const int r = m * 256 + ck * 64 + rloc;
        const float* wi = Wi + (size_t)r * En;
        const float* wh = Wh + (size_t)r * Hn;
        float acc = 0.0f;
        #pragma unroll
        for (int i = 0; i < 4; ++i) {
          const int k = lane8 * 4 + i * 32;
          const float4 w4 = *(const float4*)&wi[k];
          const float4 x4 = *(const float4*)&x_s[k];
          acc = fmaf(w4.x, x4.x, fmaf(w4.y, x4.y, fmaf(w4.z, x4.z, fmaf(w4.w, x4.w, acc))));
        }
        #pragma unroll
        for (int i = 0; i < 8; ++i) {
          const int k = lane8 * 4 + i * 32;
          const float4 w4 = *(const float4*)&wh[k];
          const float4 x4 = *(const float4*)&x_s[128 + k];
          acc = fmaf(w4.x, x4.x, fmaf(w4.y, x4.y, fmaf(w4.z, x4.z, fmaf(w4.w, x4.w, acc))));
        }
        acc += __shfl_xor(acc, 1, 64);
        acc += __shfl_xor(acc, 2, 64);
        acc += __shfl_xor(acc, 4, 64);
        gacc[m] = acc;
      }
      if (lane8 == 0) {
        #pragma unroll
        for (int m = 0; m < 4; ++m) gsum[m * 64 + rloc] = gacc[m];
      }
      __syncthreads();
      if (tid < 64) {
        const float iv = gsum[tid]       + bsum_s[tid];
        const float fv = gsum[64 + tid]  + bsum_s[64 + tid];
        const float gv = gsum[128 + tid] + bsum_s[128 + tid];
        const float ov = gsum[192 + tid] + bsum_s[192 + tid];
        const float cold = c_s[tid];
        const float cn = sigmoidf_(fv) * cold + sigmoidf_(iv) * tanhf(gv);
        const float htv = sigmoidf_(ov) * tanhf(cn);
        c_s[tid] = cn;
        htl_s[tid] = htv;
        llc_storef(wg + WG_HT + ck * 64 + tid, htv);
        if (t == Tn - 1) out[CF_OFF + (size_t)b * Hn + ck * 64 + tid] = cn;
      }
      __syncthreads();
      // inp partial: P_ck[g] = Wain[g, 64ck:64ck+64] . htl  (64 KB col-slice)
      if (tid < 256) {
        const float* wa = Wain + (size_t)tid * Hn + ck * 64;
        float acc = 0.0f;
        #pragma unroll
        for (int i = 0; i < 16; ++i) {
          const float4 w4 = *(const float4*)&wa[i * 4];
          const float4 x4 = *(const float4*)&htl_s[i * 4];
          acc = fmaf(w4.x, x4.x, fmaf(w4.y, x4.y, fmaf(w4.z, x4.z, fmaf(w4.w, x4.w, acc))));
        }
        llc_storef(wg + WG_P + ck * 256 + tid, acc);
      }
    }
    group_barrier(flags_g, ck, tgt++);

    // ============ Phase B: inp sum, scores slice, local stats, PV partial ============
    {
      if (tid < 256) {
        ht_s[tid] = llc_loadf(wg + WG_HT + tid);
      } else {
        const int gg = tid - 256;
        float s = bain_s[gg];
        s += llc_loadf(wg + WG_P + gg);
        s += llc_loadf(wg + WG_P + 256 + gg);
        s += llc_loadf(wg + WG_P + 512 + gg);
        s += llc_loadf(wg + WG_P + 768 + gg);
        inp_s[gg] = s;
      }
      __syncthreads();
      {
        const int l = tid >> 2, q = tid & 3;
        float p = 0.0f;
        #pragma unroll
        for (int i = 0; i < 16; ++i) {
          const int h4 = q * 64 + i * 4;
          const float4 c4 = *(const float4*)&ctx[l * CTX_LD + h4];
          const float4 in4 = *(const float4*)&inp_s[h4];
          const float4 v4 = *(const float4*)&V_s[h4];
          p = fmaf(v4.x, fast_tanh(in4.x + c4.x), p);
          p = fmaf(v4.y, fast_tanh(in4.y + c4.y), p);
          p = fmaf(v4.z, fast_tanh(in4.z + c4.z), p);
          p = fmaf(v4.w, fast_tanh(in4.w + c4.w), p);
        }
        p += __shfl_xor(p, 1, 64);
        p += __shfl_xor(p, 2, 64);
        if (q == 0) s_s[l] = (mask_s[l] == 0.0f) ? -INFINITY : p;
      }
      __syncthreads();
      if (tid < 128) {
        float v = s_s[tid];
        #pragma unroll
        for (int m = 1; m < 64; m <<= 1) v = fmaxf(v, __shfl_xor(v, m, 64));
        if ((tid & 63) == 0) wred[tid >> 6] = v;
      }
      __syncthreads();
      if (tid == 0) {
        const float mv = fmaxf(wred[0], wred[1]);
        wred[2] = mv;
        llc_storef(wg + WG_M + ck, mv);
      }
      __syncthreads();
      if (tid < 128) {
        const float mv = wred[2];
        const float sv = s_s[tid];
        const float e = (mask_s[tid] == 0.0f) ? 0.0f : expf(sv - mv);
        e_s[tid] = e;
        float ssum = e;
        #pragma unroll
        for (int m = 1; m < 64; m <<= 1) ssum += __shfl_xor(ssum, m, 64);
        float cv = sv; int ci = tid;
        #pragma unroll
        for (int m = 1; m < 64; m <<= 1) {
          const float ov = __shfl_xor(cv, m, 64);
          const int   oi = __shfl_xor(ci, m, 64);
          if (ov > cv || (ov == cv && oi < ci)) { cv = ov; ci = oi; }
        }
        if ((tid & 63) == 0) {
          wred[4 + (tid >> 6)] = ssum;
          wred[8 + (tid >> 6)] = cv;
          wredi[12 + (tid >> 6)] = ci;
        }
      }
      __syncthreads();
      if (tid == 0) {
        llc_storef(wg + WG_S + ck, wred[4] + wred[5]);
        float bv = wred[8]; int bI = wredi[12];
        const float v1 = wred[9]; const int i1 = wredi[13];
        if (v1 > bv || (v1 == bv && i1 < bI)) { bv = v1; bI = i1; }
        llc_storef(wg + WG_CV + ck, bv);
        llc_storei(wg_ci + ck, l0 + bI);
      }
      {
        const int h4g = tid & 63, lgq = tid >> 6;
        float p0 = 0, p1 = 0, p2 = 0, p3 = 0;
        #pragma unroll
        for (int li = 0; li < 16; ++li) {
          const int l = lgq * 16 + li;
          const float ev = e_s[l];
          const float4 c4 = *(const float4*)&ctx[l * CTX_LD + h4g * 4];
          p0 = fmaf(ev, c4.x, p0);
          p1 = fmaf(ev, c4.y, p1);
          p2 = fmaf(ev, c4.z, p2);
          p3 = fmaf(ev, c4.w, p3);
        }
        *(float4*)&scr[lgq * 256 + h4g * 4] = make_float4(p0, p1, p2, p3);
      }
      __syncthreads();
      if (tid < 256) {
        float a = 0.0f;
        #pragma unroll
        for (int r2 = 0; r2 < 8; ++r2) a += scr[r2 * 256 + tid];
        llc_storef(wg + WG_ATT + ck * 256 + tid, a);
      }
    }
    group_barrier(flags_g, ck, tgt++);

    // ============ Phase C: merge softmax, alphas, pointer, mask, u, hidden ============
    {
      if (tid < 4) {
        wred[16 + tid] = llc_loadf(wg + WG_M + tid);
        wred[20 + tid] = llc_loadf(wg + WG_S + tid);
        wred[24 + tid] = llc_loadf(wg + WG_CV + tid);
        wredi[28 + tid] = llc_loadi(wg_ci + tid);
      }
      __syncthreads();
      const float M = fmaxf(fmaxf(wred[16], wred[17]), fmaxf(wred[18], wred[19]));
      const float sc0 = expf(wred[16] - M), sc1 = expf(wred[17] - M);
      const float sc2 = expf(wred[18] - M), sc3 = expf(wred[19] - M);
      const float S_tot = fmaf(sc0, wred[20], fmaf(sc1, wred[21], fmaf(sc2, wred[22], sc3 * wred[23])));
      const float sck = (ck == 0) ? sc0 : (ck == 1) ? sc1 : (ck == 2) ? sc2 : sc3;
      if (tid < 128)
        out[(size_t)b * Ln * Ln + (size_t)t * Ln + l0 + tid] = e_s[tid] * (sck / S_tot);
      {
        float bv = wred[24]; int bI = wredi[28];
        #pragma unroll
        for (int k2 = 1; k2 < 4; ++k2) {
          const float v2 = wred[24 + k2];
          const int i2 = wredi[28 + k2];
          if (v2 > bv || (v2 == bv && i2 < bI)) { bv = v2; bI = i2; }
        }
        widx = bI;
      }
      if (tid == 0) {
        if (widx >= l0 && widx < l0 + 128) mask_s[widx - l0] = 0.0f;
        if (ck == 0) out[PTR_OFF + (size_t)b * Ln + t] = (float)widx;
      }
      if (tid < 256) {
        const float a = fmaf(llc_loadf(wg + WG_ATT + tid), sc0,
                        fmaf(llc_loadf(wg + WG_ATT + 256 + tid), sc1,
                        fmaf(llc_loadf(wg + WG_ATT + 512 + tid), sc2,
                             llc_loadf(wg + WG_ATT + 768 + tid) * sc3)));
        u_s[tid] = a / S_tot;
      } else {
        u_s[tid] = ht_s[tid - 256];
      }
      __syncthreads();
      {
        const int row = ck * 64 + rloc;
        const float* wo = Wo + (size_t)row * (2 * Hn);
        float acc = 0.0f;
        #pragma unroll
        for (int i = 0; i < 16; ++i) {
          const int k = lane8 * 4 + i * 32;
          const float4 w4 = *(const float4*)&wo[k];
          const float4 x4 = *(const float4*)&u_s[k];
          acc = fmaf(w4.x, x4.x, fmaf(w4.y, x4.y, fmaf(w4.z, x4.z, fmaf(w4.w, x4.w, acc))));
        }
        acc += __shfl_xor(acc, 1, 64);
        acc += __shfl_xor(acc, 2, 64);
        acc += __shfl_xor(acc, 4, 64);
        if (lane8 == 0) {
          const float hv = tanhf(acc + bo_s[rloc]);
          llc_storef(wg + WG_HID + row, hv);
          if (t == Tn - 1) out[HF_OFF + (size_t)b * Hn + row] = hv;
        }
      }
    }
    group_barrier(flags_g, ck, tgt++);
  }
}

extern "C" void kernel_launch(void* const* d_in, const int* in_sizes, int n_in,
                              void* d_out, int out_size, void* d_ws, size_t ws_size,
                              hipStream_t stream) {
  (void)in_sizes; (void)n_in; (void)out_size; (void)ws_size;
  hipFuncSetAttribute(reinterpret_cast<const void*>(decoder_main),
                      hipFuncAttributeMaxDynamicSharedMemorySize, SMEM_FL * 4);
  hipMemsetAsync(d_ws, 0, 32768, stream);

  const float* emb   = (const float*)d_in[0];
  const float* dec0  = (const float*)d_in[1];
  const float* h0    = (const float*)d_in[2];
  const float* c0    = (const float*)d_in[3];
  const float* ctxg  = (const float*)d_in[4];
  const float* Wi    = (const float*)d_in[5];
  const float* bi    = (const float*)d_in[6];
  const float* Wh    = (const float*)d_in[7];
  const float* bh    = (const float*)d_in[8];
  const float* Wo    = (const float*)d_in[9];
  const float* bo    = (const float*)d_in[10];
  const float* Wain  = (const float*)d_in[11];
  const float* bain  = (const float*)d_in[12];
  const float* Wactx = (const float*)d_in[13];
  const float* bactx = (const float*)d_in[14];
  const float* V     = (const float*)d_in[15];

  unsigned* flags = (unsigned*)d_ws;
  float* wsd = (float*)d_ws + 8192;

  decoder_main<<<NBLK, NTHR, SMEM_FL * 4, stream>>>(
      emb, dec0, h0, c0, ctxg, Wi, bi, Wh, bh, Wo, bo, Wain, bain, Wactx, bactx, V,
      (float*)d_out, flags, wsd);
}

// Round 4
// 13182.146 us; speedup vs baseline: 4.9888x; 1.4062x over previous
//
#include <hip/hip_runtime.h>
#include <math.h>

#define SCOPE __HIP_MEMORY_SCOPE_AGENT

constexpr int Bn = 64, Ln = 512, En = 128, Hn = 256, Tn = 512;
constexpr int NBLK = 256, NTHR = 512;
constexpr int CTX_LD = 260;
constexpr int XPAD = 392, HTPAD = 264, UPAD = 520;

// ---- LDS layout (floats) ----
constexpr int OFF_CTX = 0;                    // [128][260] ctx slice
constexpr int OFF_SCR = 128 * CTX_LD;         // 4096 union: init stage / gates stage / PV / u / x
constexpr int OFF_HT  = OFF_SCR + 4096;       // h_t [4][264]
constexpr int OFF_INP = OFF_HT + 4 * HTPAD;   // inp (own batch) [256]
constexpr int OFF_SS  = OFF_INP + 256;        // scores [128]
constexpr int OFF_ES  = OFF_SS + 128;         // e [128]
constexpr int OFF_MK  = OFF_ES + 128;         // mask [128]
constexpr int OFF_VS  = OFF_MK + 128;         // V [256]
constexpr int OFF_ST  = OFF_VS + 256;         // stats [64]
constexpr int OFF_WR  = OFF_ST + 64;          // reduce scratch [64]
constexpr int OFF_X   = OFF_SCR;              // x [4][392] aliases scr (phase A)
constexpr int SMEM_FL = OFF_WR + 64;          // 39456 floats = 157824 B

// ---- output layout ----
constexpr size_t PTR_OFF = (size_t)Bn * Ln * Ln;
constexpr size_t HF_OFF  = PTR_OFF + (size_t)Bn * Ln;
constexpr size_t CF_OFF  = HF_OFF + (size_t)Bn * Hn;

// ---- ws: [0,32KB) flags (256 blocks x 32 uints); then per-group float region ----
constexpr int GQ_GATES = 0;       // [16 j][4 bb][64 rloc] final pre-activations (+bias)
constexpr int GQ_INP   = 4096;    // [16 j][4 bb][16]     final inp rows (+bain)
constexpr int GQ_ST    = 5120;    // [4 bb][4 ck][4] {m, S, candv, candi-as-float}
constexpr int GQ_ATT   = 5184;    // [4 bb][4 ck][256]    PV partials
constexpr int GQ_HID   = 9280;    // [16 j][4 bb][16]     final hidden rows
constexpr int GQ_STRIDE = 10368;

__device__ __forceinline__ float fast_tanh(float x) {
  const float e = __expf(2.0f * x);
  return 1.0f - __fdividef(2.0f, 1.0f + e);
}
__device__ __forceinline__ float sigmoidf_(float x) {
  return 1.0f / (1.0f + expf(-x));
}
// relaxed agent-scope (LLC) accessors: no cache invalidation
__device__ __forceinline__ void llc_storef(float* p, float v) {
  __hip_atomic_store(p, v, __ATOMIC_RELAXED, SCOPE);
}
__device__ __forceinline__ float llc_loadf(const float* p) {
  return __hip_atomic_load(p, __ATOMIC_RELAXED, SCOPE);
}
__device__ __forceinline__ unsigned long long llc_loadu64(const unsigned long long* p) {
  return __hip_atomic_load(p, __ATOMIC_RELAXED, SCOPE);
}

// 16-block group barrier: relaxed LLC flag per member; vmcnt(0) drained before
// the flag store so all data stores are acked at the coherence point first.
__device__ __forceinline__ void group_barrier16(unsigned* flags_g, int j, unsigned tgt) {
  asm volatile("s_waitcnt vmcnt(0)" ::: "memory");
  __syncthreads();
  if (threadIdx.x == 0)
    __hip_atomic_store(&flags_g[j * 32], tgt, __ATOMIC_RELAXED, SCOPE);
  if (threadIdx.x < 16) {
    long spins = 0;
    while (__hip_atomic_load(&flags_g[threadIdx.x * 32], __ATOMIC_RELAXED, SCOPE) < tgt) {
      __builtin_amdgcn_s_sleep(2);
      if (++spins > 50000000L) __builtin_trap();
    }
  }
  __syncthreads();
  asm volatile("" ::: "memory");
}

#define DOT4(acc, w4, x4) \
  acc = fmaf((w4).x, (x4).x, fmaf((w4).y, (x4).y, fmaf((w4).z, (x4).z, fmaf((w4).w, (x4).w, (acc)))))

__global__ void __launch_bounds__(NTHR, 2)
decoder_main(const float* __restrict__ emb, const float* __restrict__ dec0,
             const float* __restrict__ h0,  const float* __restrict__ c0,
             const float* __restrict__ ctxg,const float* __restrict__ Wi,
             const float* __restrict__ bi,  const float* __restrict__ Wh,
             const float* __restrict__ bh,  const float* __restrict__ Wo,
             const float* __restrict__ bo,  const float* __restrict__ Wain,
             const float* __restrict__ bain,const float* __restrict__ Wactx,
             const float* __restrict__ bactx,const float* __restrict__ Vv,
             float* __restrict__ out, unsigned* __restrict__ flags,
             float* __restrict__ wsd)
{
  extern __shared__ float sm[];
  float* ctx    = sm + OFF_CTX;
  float* scr    = sm + OFF_SCR;
  float* x_s    = sm + OFF_X;
  float* h_t_s  = sm + OFF_HT;
  float* inp_s  = sm + OFF_INP;
  float* s_s    = sm + OFF_SS;
  float* e_s    = sm + OFF_ES;
  float* mask_s = sm + OFF_MK;
  float* V_s    = sm + OFF_VS;
  float* stats_s= sm + OFF_ST;
  float* wred   = sm + OFF_WR;
  int*   wredi  = (int*)wred;

  const int tid = threadIdx.x, bid = blockIdx.x;
  const int gq = bid >> 4, j = bid & 15;
  const int bbj = j >> 2, ck = j & 3;
  const int b_ctx = gq * 4 + bbj;
  const int l0 = ck * 128;

  const int rloc = tid >> 3, seg8 = tid & 7;       // gates teams (8 thr/row)
  const int r_abs = j * 64 + rloc;                 // gate row in [0,1024)
  const int r16loc = tid >> 5, seg32 = tid & 31;   // Wain/Wo teams (32 thr/row)
  const int r16 = j * 16 + r16loc;                 // row in [0,256)

  unsigned* flags_g = flags + gq * (16 * 32);
  float* wsg = wsd + (size_t)gq * GQ_STRIDE;

  // ---- weight registers (one-time load; reused 4 batches x 512 steps) ----
  float4 wg4[12];
  #pragma unroll
  for (int k = 0; k < 12; ++k) {
    if (k < 4) wg4[k] = *(const float4*)&Wi[(size_t)r_abs * En + k * 32 + seg8 * 4];
    else       wg4[k] = *(const float4*)&Wh[(size_t)r_abs * Hn + (k - 4) * 32 + seg8 * 4];
  }
  const float bias_g = bi[r_abs] + bh[r_abs];
  float4 wa4[2];
  #pragma unroll
  for (int k = 0; k < 2; ++k) wa4[k] = *(const float4*)&Wain[(size_t)r16 * Hn + k * 128 + seg32 * 4];
  float4 wo4[4];
  #pragma unroll
  for (int k = 0; k < 4; ++k) wo4[k] = *(const float4*)&Wo[(size_t)r16 * (2 * Hn) + k * 128 + seg32 * 4];
  const float bain_r = bain[r16];
  const float bo_r = bo[r16];

  // replicated cell state: thread owns (b2c, hc) and (b2c, hc+1)
  const int b2c = tid >> 7;
  const int hc = (2 * tid) & 255;
  float c0a = c0[(size_t)(gq * 4 + b2c) * Hn + hc];
  float c1a = c0[(size_t)(gq * 4 + b2c) * Hn + hc + 1];

  if (tid < 128) mask_s[tid] = 1.0f;
  if (tid < 256) V_s[tid] = Vv[tid];

  // ---- one-time ctx_proj slice into LDS (batch b_ctx, l in [l0,l0+128)) ----
  {
    const int gc = tid & 31, lg = tid >> 5;
    float acc[8][8];
    #pragma unroll
    for (int a2 = 0; a2 < 8; ++a2)
      #pragma unroll
      for (int b2 = 0; b2 < 8; ++b2) acc[a2][b2] = 0.0f;
    float* stg_c = scr;
    float* stg_w = scr + 1024;
    for (int kc = 0; kc < 32; ++kc) {
      __syncthreads();
      for (int i = tid; i < 1024; i += NTHR) {
        int k = i & 7, l = i >> 3;
        stg_c[k * 128 + l] = ctxg[((size_t)(b_ctx * Ln + l0 + l)) * Hn + kc * 8 + k];
      }
      for (int i = tid; i < 2048; i += NTHR) {
        int k = i & 7, gg = i >> 3;
        stg_w[k * 256 + gg] = Wactx[(size_t)gg * Hn + kc * 8 + k];
      }
      __syncthreads();
      #pragma unroll
      for (int kk = 0; kk < 8; ++kk) {
        float cl[8], wgt[8];
        #pragma unroll
        for (int jj = 0; jj < 8; ++jj) cl[jj] = stg_c[kk * 128 + lg * 8 + jj];
        #pragma unroll
        for (int jj = 0; jj < 8; ++jj) wgt[jj] = stg_w[kk * 256 + gc * 8 + jj];
        #pragma unroll
        for (int li = 0; li < 8; ++li)
          #pragma unroll
          for (int gi = 0; gi < 8; ++gi)
            acc[li][gi] = fmaf(cl[li], wgt[gi], acc[li][gi]);
      }
    }
    __syncthreads();
    #pragma unroll
    for (int li = 0; li < 8; ++li)
      #pragma unroll
      for (int gi = 0; gi < 8; ++gi)
        ctx[(lg * 8 + li) * CTX_LD + gc * 8 + gi] = acc[li][gi] + bactx[gc * 8 + gi];
  }
  __syncthreads();

  unsigned tgt = 1;
  int w0 = 0, w1 = 0, w2 = 0, w3 = 0;   // per-batch pointer from previous step

  for (int t = 0; t < Tn; ++t) {
    // ========== Phase A: stage x, gates GEMV (reg weights), publish ==========
    {
      for (int i = tid; i < 4 * 384; i += NTHR) {
        const int bb = i / 384, c = i - bb * 384;
        const int gb = gq * 4 + bb;
        float v;
        if (c < 128) {
          if (t == 0) v = dec0[(size_t)gb * En + c];
          else {
            const int wsel = (bb == 0) ? w0 : (bb == 1) ? w1 : (bb == 2) ? w2 : w3;
            v = emb[((size_t)gb * Ln + wsel) * En + c];
          }
        } else {
          const int h = c - 128;
          v = (t == 0) ? h0[(size_t)gb * Hn + h]
                       : llc_loadf(wsg + GQ_HID + (h >> 4) * 64 + bb * 16 + (h & 15));
        }
        x_s[bb * XPAD + c] = v;
      }
      __syncthreads();
      #pragma unroll
      for (int bb = 0; bb < 4; ++bb) {
        float acc = 0.0f;
        #pragma unroll
        for (int k = 0; k < 12; ++k) {
          const float4 x4 = *(const float4*)&x_s[bb * XPAD + k * 32 + seg8 * 4];
          DOT4(acc, wg4[k], x4);
        }
        acc += __shfl_xor(acc, 1, 64);
        acc += __shfl_xor(acc, 2, 64);
        acc += __shfl_xor(acc, 4, 64);
        if (seg8 == 0)
          llc_storef(wsg + GQ_GATES + j * 256 + bb * 64 + rloc, acc + bias_g);
      }
    }
    group_barrier16(flags_g, j, tgt++);

    // ========== Phase B: stage gates, replicated cell, h_t -> LDS, Wain rows ==========
    {
      unsigned long long* scr64 = (unsigned long long*)scr;
      const unsigned long long* src64 = (const unsigned long long*)(wsg + GQ_GATES);
      for (int i = tid; i < 2048; i += NTHR) scr64[i] = llc_loadu64(src64 + i);
      __syncthreads();
      {
        const int i0 = (hc >> 6) * 256 + b2c * 64 + (hc & 63);
        const float iv0 = scr[i0],        fv0 = scr[1024 + i0];
        const float gv0 = scr[2048 + i0], ov0 = scr[3072 + i0];
        const float iv1 = scr[i0 + 1],        fv1 = scr[1024 + i0 + 1];
        const float gv1 = scr[2048 + i0 + 1], ov1 = scr[3072 + i0 + 1];
        const float cn0 = sigmoidf_(fv0) * c0a + sigmoidf_(iv0) * tanhf(gv0);
        const float ht0 = sigmoidf_(ov0) * tanhf(cn0);
        const float cn1 = sigmoidf_(fv1) * c1a + sigmoidf_(iv1) * tanhf(gv1);
        const float ht1 = sigmoidf_(ov1) * tanhf(cn1);
        c0a = cn0; c1a = cn1;
        h_t_s[b2c * HTPAD + hc] = ht0;
        h_t_s[b2c * HTPAD + hc + 1] = ht1;
        if (t == Tn - 1 && j == 0) {
          out[CF_OFF + (size_t)(gq * 4 + b2c) * Hn + hc] = cn0;
          out[CF_OFF + (size_t)(gq * 4 + b2c) * Hn + hc + 1] = cn1;
        }
      }
      __syncthreads();
      #pragma unroll
      for (int bb = 0; bb < 4; ++bb) {
        float acc = 0.0f;
        #pragma unroll
        for (int k = 0; k < 2; ++k) {
          const float4 x4 = *(const float4*)&h_t_s[bb * HTPAD + k * 128 + seg32 * 4];
          DOT4(acc, wa4[k], x4);
        }
        acc += __shfl_xor(acc, 1, 64);
        acc += __shfl_xor(acc, 2, 64);
        acc += __shfl_xor(acc, 4, 64);
        acc += __shfl_xor(acc, 8, 64);
        acc += __shfl_xor(acc, 16, 64);
        if (seg32 == 0)
          llc_storef(wsg + GQ_INP + j * 64 + bb * 16 + r16loc, acc + bain_r);
      }
    }
    group_barrier16(flags_g, j, tgt++);

    // ========== Phase C: gather inp(own batch), scores, local softmax, PV ==========
    {
      if (tid < 256)
        inp_s[tid] = llc_loadf(wsg + GQ_INP + (tid >> 4) * 64 + bbj * 16 + (tid & 15));
      __syncthreads();
      {
        const int l = tid >> 2, q = tid & 3;
        float p = 0.0f;
        #pragma unroll
        for (int i = 0; i < 16; ++i) {
          const int h4 = q * 64 + i * 4;
          const float4 c4 = *(const float4*)&ctx[l * CTX_LD + h4];
          const float4 in4 = *(const float4*)&inp_s[h4];
          const float4 v4 = *(const float4*)&V_s[h4];
          p = fmaf(v4.x, fast_tanh(in4.x + c4.x), p);
          p = fmaf(v4.y, fast_tanh(in4.y + c4.y), p);
          p = fmaf(v4.z, fast_tanh(in4.z + c4.z), p);
          p = fmaf(v4.w, fast_tanh(in4.w + c4.w), p);
        }
        p += __shfl_xor(p, 1, 64);
        p += __shfl_xor(p, 2, 64);
        if (q == 0) s_s[l] = (mask_s[l] == 0.0f) ? -INFINITY : p;
      }
      __syncthreads();
      if (tid < 128) {
        float v = s_s[tid];
        #pragma unroll
        for (int m = 1; m < 64; m <<= 1) v = fmaxf(v, __shfl_xor(v, m, 64));
        if ((tid & 63) == 0) wred[tid >> 6] = v;
      }
      __syncthreads();
      if (tid == 0) wred[2] = fmaxf(wred[0], wred[1]);
      __syncthreads();
      if (tid < 128) {
        const float mv = wred[2];
        const float sv = s_s[tid];
        const float e = (mask_s[tid] == 0.0f) ? 0.0f : expf(sv - mv);
        e_s[tid] = e;
        float ssum = e;
        #pragma unroll
        for (int m = 1; m < 64; m <<= 1) ssum += __shfl_xor(ssum, m, 64);
        float cv = sv; int ci = tid;
        #pragma unroll
        for (int m = 1; m < 64; m <<= 1) {
          const float ov = __shfl_xor(cv, m, 64);
          const int   oi = __shfl_xor(ci, m, 64);
          if (ov > cv || (ov == cv && oi < ci)) { cv = ov; ci = oi; }
        }
        if ((tid & 63) == 0) {
          wred[4 + (tid >> 6)] = ssum;
          wred[8 + (tid >> 6)] = cv;
          wredi[12 + (tid >> 6)] = ci;
        }
      }
      __syncthreads();
      if (tid == 0) {
        float bv = wred[8]; int bI = wredi[12];
        if (wred[9] > bv || (wred[9] == bv && wredi[13] < bI)) { bv = wred[9]; bI = wredi[13]; }
        float* stb = wsg + GQ_ST + (bbj * 4 + ck) * 4;
        llc_storef(stb + 0, wred[2]);
        llc_storef(stb + 1, wred[4] + wred[5]);
        llc_storef(stb + 2, bv);
        llc_storef(stb + 3, (float)(l0 + bI));
      }
      {
        const int h4g = tid & 63, lgq = tid >> 6;
        float p0 = 0, p1 = 0, p2 = 0, p3 = 0;
        #pragma unroll
        for (int li = 0; li < 16; ++li) {
          const int l = lgq * 16 + li;
          const float ev = e_s[l];
          const float4 c4 = *(const float4*)&ctx[l * CTX_LD + h4g * 4];
          p0 = fmaf(ev, c4.x, p0);
          p1 = fmaf(ev, c4.y, p1);
          p2 = fmaf(ev, c4.z, p2);
          p3 = fmaf(ev, c4.w, p3);
        }
        __syncthreads();   // scr free (gates staging consumed)
        *(float4*)&scr[lgq * 256 + h4g * 4] = make_float4(p0, p1, p2, p3);
      }
      __syncthreads();
      if (tid < 256) {
        float a = 0.0f;
        #pragma unroll
        for (int r2 = 0; r2 < 8; ++r2) a += scr[r2 * 256 + tid];
        llc_storef(wsg + GQ_ATT + (bbj * 4 + ck) * 256 + tid, a);
      }
    }
    group_barrier16(flags_g, j, tgt++);

    // ========== Phase D: merge stats, alphas, pointer, mask, u, Wo rows ==========
    {
      if (tid < 64) stats_s[tid] = llc_loadf(wsg + GQ_ST + tid);
      __syncthreads();
      float Mb[4], Sb[4], sc[4][4];
      int wq[4];
      #pragma unroll
      for (int bb = 0; bb < 4; ++bb) {
        const float m0 = stats_s[(bb * 4 + 0) * 4], m1 = stats_s[(bb * 4 + 1) * 4];
        const float m2 = stats_s[(bb * 4 + 2) * 4], m3 = stats_s[(bb * 4 + 3) * 4];
        const float M = fmaxf(fmaxf(m0, m1), fmaxf(m2, m3));
        const float e0 = expf(m0 - M), e1 = expf(m1 - M);
        const float e2 = expf(m2 - M), e3 = expf(m3 - M);
        Mb[bb] = M;
        Sb[bb] = fmaf(e0, stats_s[(bb * 4 + 0) * 4 + 1],
                 fmaf(e1, stats_s[(bb * 4 + 1) * 4 + 1],
                 fmaf(e2, stats_s[(bb * 4 + 2) * 4 + 1],
                      e3 * stats_s[(bb * 4 + 3) * 4 + 1])));
        sc[bb][0] = e0; sc[bb][1] = e1; sc[bb][2] = e2; sc[bb][3] = e3;
        float bv = stats_s[(bb * 4 + 0) * 4 + 2];
        int bI = (int)stats_s[(bb * 4 + 0) * 4 + 3];
        #pragma unroll
        for (int c2 = 1; c2 < 4; ++c2) {
          const float v2 = stats_s[(bb * 4 + c2) * 4 + 2];
          const int i2 = (int)stats_s[(bb * 4 + c2) * 4 + 3];
          if (v2 > bv || (v2 == bv && i2 < bI)) { bv = v2; bI = i2; }
        }
        wq[bb] = bI;
      }
      // own-batch selects (bbj, ck are wave-uniform runtime values)
      float sck_own = 0, Stot_own = 0;
      int widx_own = 0;
      #pragma unroll
      for (int bb = 0; bb < 4; ++bb)
        if (bb == bbj) {
          Stot_own = Sb[bb]; widx_own = wq[bb];
          #pragma unroll
          for (int c2 = 0; c2 < 4; ++c2)
            if (c2 == ck) sck_own = sc[bb][c2];
        }
      if (tid < 128)
        out[(size_t)b_ctx * Ln * Ln + (size_t)t * Ln + l0 + tid] = e_s[tid] * (sck_own / Stot_own);
      if (tid == 0) {
        if (widx_own >= l0 && widx_own < l0 + 128) mask_s[widx_own - l0] = 0.0f;
        if (ck == 0) out[PTR_OFF + (size_t)b_ctx * Ln + t] = (float)widx_own;
      }
      // u staging: [4][520] in scr
      #pragma unroll
      for (int bb = 0; bb < 4; ++bb) {
        float v;
        if (tid < 256) {
          const float a = fmaf(sc[bb][0], llc_loadf(wsg + GQ_ATT + (bb * 4 + 0) * 256 + tid),
                          fmaf(sc[bb][1], llc_loadf(wsg + GQ_ATT + (bb * 4 + 1) * 256 + tid),
                          fmaf(sc[bb][2], llc_loadf(wsg + GQ_ATT + (bb * 4 + 2) * 256 + tid),
                               sc[bb][3] * llc_loadf(wsg + GQ_ATT + (bb * 4 + 3) * 256 + tid))));
          v = a / Sb[bb];
        } else {
          v = h_t_s[bb * HTPAD + (tid - 256)];
        }
        scr[bb * UPAD + tid] = v;
      }
      __syncthreads();
      #pragma unroll
      for (int bb = 0; bb < 4; ++bb) {
        float acc = 0.0f;
        #pragma unroll
        for (int k = 0; k < 4; ++k) {
          const float4 x4 = *(const float4*)&scr[bb * UPAD + k * 128 + seg32 * 4];
          DOT4(acc, wo4[k], x4);
        }
        acc += __shfl_xor(acc, 1, 64);
        acc += __shfl_xor(acc, 2, 64);
        acc += __shfl_xor(acc, 4, 64);
        acc += __shfl_xor(acc, 8, 64);
        acc += __shfl_xor(acc, 16, 64);
        if (seg32 == 0) {
          const float hv = tanhf(acc + bo_r);
          llc_storef(wsg + GQ_HID + j * 64 + bb * 16 + r16loc, hv);
          if (t == Tn - 1) out[HF_OFF + (size_t)(gq * 4 + bb) * Hn + r16] = hv;
        }
      }
      w0 = wq[0]; w1 = wq[1]; w2 = wq[2]; w3 = wq[3];
    }
    group_barrier16(flags_g, j, tgt++);
  }
}

extern "C" void kernel_launch(void* const* d_in, const int* in_sizes, int n_in,
                              void* d_out, int out_size, void* d_ws, size_t ws_size,
                              hipStream_t stream) {
  (void)in_sizes; (void)n_in; (void)out_size; (void)ws_size;
  hipFuncSetAttribute(reinterpret_cast<const void*>(decoder_main),
                      hipFuncAttributeMaxDynamicSharedMemorySize, SMEM_FL * 4);
  hipMemsetAsync(d_ws, 0, 32768, stream);

  const float* emb   = (const float*)d_in[0];
  const float* dec0  = (const float*)d_in[1];
  const float* h0    = (const float*)d_in[2];
  const float* c0    = (const float*)d_in[3];
  const float* ctxg  = (const float*)d_in[4];
  const float* Wi    = (const float*)d_in[5];
  const float* bi    = (const float*)d_in[6];
  const float* Wh    = (const float*)d_in[7];
  const float* bh    = (const float*)d_in[8];
  const float* Wo    = (const float*)d_in[9];
  const float* bo    = (const float*)d_in[10];
  const float* Wain  = (const float*)d_in[11];
  const float* bain  = (const float*)d_in[12];
  const float* Wactx = (const float*)d_in[13];
  const float* bactx = (const float*)d_in[14];
  const float* V     = (const float*)d_in[15];

  unsigned* flags = (unsigned*)d_ws;
  float* wsd = (float*)((char*)d_ws + 32768);

  decoder_main<<<NBLK, NTHR, SMEM_FL * 4, stream>>>(
      emb, dec0, h0, c0, ctxg, Wi, bi, Wh, bh, Wo, bo, Wain, bain, Wactx, bactx, V,
      (float*)d_out, flags, wsd);
}